// Round 6
// baseline (542.651 us; speedup 1.0000x reference)
//
#include <hip/hip_runtime.h>

#define TAGS 64
#define MAXT 512
#define NEG  -10000.0f
#define CH   8   // steps per chunk/phase

// Round-12: producer/consumer split, third attempt — both round-5 defects
// fixed. (r5 post-mortem: VGPR_Count=88 starved the 16-deep ds_read ILP,
// ~1814 cyc/step; 50KB LDS -> 3 blocks/CU broke full residency.)
//   fix 1: __launch_bounds__(192, 1) -> VGPR cap 512, natural pressure ~160
//          (<=170 keeps 12 waves/CU inside the 2048-reg budget).
//   fix 2: LDS = 37.75 KB -> 4 blocks/CU, all 1024 blocks resident:
//          feats prefetched to producer REGISTERS (round-1-verified), pub
//          ring holds fv only (4 KB), consumers recompute m via the max
//          tree (fmax over the same set is order-independent => exact).
// Theory under test (fits r0/r1/r3 within 10%): per-wave issue cadence ~4
// cyc/instr at 1-wave/SIMD; per-step time = 4 x serial-wave instr count.
// Producer runs only the value recurrence (~135 instr/step ~540 cyc);
// waves 1-2 trail one chunk, recompute c[] from published fv (bit-identical
// adds), redo the max tree, and run the round-3-verified bitwise
// first-occurrence scan + bptr write (~273 instr x 4 steps each ~= producer).
// Ring safety: phase c producer writes pub[c&1] + seed[c%3]; consumers read
// pub[(c-1)&1] + seed[(c+1)%3] ((c-2)%3). Disjoint; 1 barrier/phase.
__global__ __launch_bounds__(192, 1) void crf_viterbi(
    const float* __restrict__ feats,   // [B, T, K]
    const float* __restrict__ weights, // [K, K] (weights[next][prev])
    const int*   __restrict__ lens,    // [B]
    float*       __restrict__ out,     // [B] scores ++ [B*T] paths (as f32)
    int B, int T)
{
    const int b    = blockIdx.x;
    const int tid  = threadIdx.x;
    const int wv   = tid >> 6;                 // 0 = producer, 1..2 = consumers
    const int lane = tid & 63;                 // next tag
    const int len  = lens[b];                  // 1..T

    __shared__ float pub[2][CH][TAGS];           // 4 KB   published fv ring
    __shared__ float seed[3][TAGS];              // 768 B  chunk-boundary fv
    __shared__ unsigned char  bptr[MAXT * TAGS]; // 32 KB
    __shared__ unsigned short path[MAXT];        // 1 KB
    // total 38656 B -> 4 blocks/CU (12 waves/CU)

#define F3(a, b, c) fmaxf(fmaxf((a), (b)), (c))
#define M3(a, b, c) min(min((a), (b)), (c))

    // W row for this lane (producer adds it; consumers re-add identically)
    float4 w4[16];
    #pragma unroll
    for (int i = 0; i < 16; ++i)
        w4[i] = *reinterpret_cast<const float4*>(weights + lane * TAGS + i * 4);
    const float wEnd = weights[1 * TAGS + lane];  // transition into END

    const float* fb  = feats + (size_t)b * T * TAGS;
    const int    cap = len * TAGS;                // valid dword count
    const int    nch = (len + CH - 1) / CH;

    float nf = NEG;                               // producer's running fv
    float fcur[CH], fnx[CH];                      // producer feat prefetch

    if (wv == 0) {
        const float init = (lane == 0) ? 0.0f : NEG;
        pub[1][CH - 1][lane] = init;              // producer's i=0 source, c=0
        seed[2][lane]        = init;              // consumers' i=0 source, c=1
        #pragma unroll
        for (int i = 0; i < CH; ++i) {
            int o = i * TAGS + lane; if (o >= cap) o = lane;
            fcur[i] = fb[o];
        }
        #pragma unroll
        for (int i = 0; i < CH; ++i) {
            int o = (CH + i) * TAGS + lane; if (o >= cap) o = lane;
            fnx[i] = fb[o];
        }
    }
    // consumers first touch pub/seed at phase 1, after the phase-0 barrier.

    int m3 = 0;                                   // c % 3
    for (int c = 0; c <= nch; ++c) {
        if (wv == 0) {
            if (c < nch) {
                // ---- producer: value recurrence for chunk c ----
                const int    n     = min(CH, len - c * CH);
                float*       cur   = &pub[c & 1][0][0];
                const float* prev0 = &pub[(c + 1) & 1][CH - 1][0]; // == (c-1)&1
                #pragma unroll
                for (int i = 0; i < CH; ++i) {
                    if (i < n) {
                        const float* fvp = (i == 0) ? prev0 : (cur + (i - 1) * TAGS);
                        float4 fq[16];
                        #pragma unroll
                        for (int g = 0; g < 16; ++g)
                            fq[g] = *reinterpret_cast<const float4*>(fvp + 4 * g);
                        float4 c4[16];
                        #pragma unroll
                        for (int g = 0; g < 16; ++g) {
                            c4[g].x = fq[g].x + w4[g].x;
                            c4[g].y = fq[g].y + w4[g].y;
                            c4[g].z = fq[g].z + w4[g].z;
                            c4[g].w = fq[g].w + w4[g].w;
                        }
                        const float* cc = reinterpret_cast<const float*>(c4);
                        float v1[22];
                        #pragma unroll
                        for (int k = 0; k < 21; ++k) v1[k] = F3(cc[3*k], cc[3*k+1], cc[3*k+2]);
                        v1[21] = cc[63];
                        float v2[8];
                        #pragma unroll
                        for (int k = 0; k < 7; ++k) v2[k] = F3(v1[3*k], v1[3*k+1], v1[3*k+2]);
                        v2[7] = v1[21];
                        const float v30 = F3(v2[0], v2[1], v2[2]);
                        const float v31 = F3(v2[3], v2[4], v2[5]);
                        const float v32 = fmaxf(v2[6], v2[7]);
                        const float m   = F3(v30, v31, v32);

                        nf = m + fcur[i];                  // emission after max
                        cur[i * TAGS + lane] = nf;         // publish fv(t)
                    }
                }
                seed[m3][lane] = nf;                       // last fv of chunk c
                // rotate feat prefetch: fcur <- fnx, issue chunk c+2
                #pragma unroll
                for (int i = 0; i < CH; ++i) fcur[i] = fnx[i];
                #pragma unroll
                for (int i = 0; i < CH; ++i) {
                    int o = (c + 2) * CH * TAGS + i * TAGS + lane;
                    if (o >= cap) o = lane;
                    fnx[i] = fb[o];
                }
            }
        } else if (c > 0) {
            // ---- consumers: argmax + bptr for chunk c-1 ----
            const int    ck    = c - 1;
            const int    n     = min(CH, len - ck * CH);
            const float* base  = &pub[ck & 1][0][0];
            const float* prev0 = &seed[(m3 + 1) % 3][0];   // fv of step ck*CH-1
            for (int i = wv - 1; i < n; i += 2) {
                const float* fvp = (i == 0) ? prev0 : (base + (i - 1) * TAGS);
                float cv[64];
                #pragma unroll
                for (int g = 0; g < 16; ++g) {
                    const float4 fq = *reinterpret_cast<const float4*>(fvp + 4 * g);
                    cv[4*g+0] = fq.x + w4[g].x;
                    cv[4*g+1] = fq.y + w4[g].y;
                    cv[4*g+2] = fq.z + w4[g].z;
                    cv[4*g+3] = fq.w + w4[g].w;
                }
                // recompute m (exact: fmax over same set, any order)
                float v1[22];
                #pragma unroll
                for (int k = 0; k < 21; ++k) v1[k] = F3(cv[3*k], cv[3*k+1], cv[3*k+2]);
                v1[21] = cv[63];
                float v2[8];
                #pragma unroll
                for (int k = 0; k < 7; ++k) v2[k] = F3(v1[3*k], v1[3*k+1], v1[3*k+2]);
                v2[7] = v1[21];
                const float mm = F3(F3(v2[0], v2[1], v2[2]),
                                    F3(v2[3], v2[4], v2[5]),
                                    fmaxf(v2[6], v2[7]));
                // bitwise first-occurrence scan (round-3-verified):
                // key = (bits(mm - cv[p]) & ~63) | p ; winner's key == p
                unsigned q[16];
                #pragma unroll
                for (int g = 0; g < 16; ++g) {
                    const unsigned k0 = (__float_as_uint(mm - cv[4*g+0]) & 0xFFFFFFC0u) | (unsigned)(4*g+0);
                    const unsigned k1 = (__float_as_uint(mm - cv[4*g+1]) & 0xFFFFFFC0u) | (unsigned)(4*g+1);
                    const unsigned k2 = (__float_as_uint(mm - cv[4*g+2]) & 0xFFFFFFC0u) | (unsigned)(4*g+2);
                    const unsigned k3 = (__float_as_uint(mm - cv[4*g+3]) & 0xFFFFFFC0u) | (unsigned)(4*g+3);
                    q[g] = min(M3(k0, k1, k2), k3);
                }
                const unsigned t0 = M3(q[0],  q[1],  q[2]);
                const unsigned t1 = M3(q[3],  q[4],  q[5]);
                const unsigned t2 = M3(q[6],  q[7],  q[8]);
                const unsigned t3 = M3(q[9],  q[10], q[11]);
                const unsigned t4 = M3(q[12], q[13], q[14]);
                const unsigned idx = min(M3(t0, t1, t2), M3(t3, t4, q[15]));
                bptr[(ck * CH + i) * TAGS + lane] = (unsigned char)idx;
            }
        }
        __syncthreads();
        m3 = (m3 == 2) ? 0 : m3 + 1;
    }

    if (wv != 0) return;   // consumers done (final barrier already passed)

    // terminal = fv + W[END][prev]; first-max argmax via shuffle butterfly
    float tv = nf + wEnd;
    int   ti = lane;
    #pragma unroll
    for (int off = 32; off >= 1; off >>= 1) {
        const float ov = __shfl_xor(tv, off);
        const int   oi = __shfl_xor(ti, off);
        if (ov > tv || (ov == tv && oi < ti)) { tv = ov; ti = oi; }
    }
    if (lane == 0) out[b] = tv;
    const int bestlast = ti;                      // uniform across lanes

    // padding region: path[t] = bestlast for t in [len-1, T)
    for (int t = lane; t < T; t += 64)
        if (t >= len - 1) path[t] = (unsigned short)bestlast;
    __builtin_amdgcn_wave_barrier();

    // serial chase (lane 0, LDS-resident backpointers)
    if (lane == 0) {
        int tag = bestlast;
        for (int t = len - 1; t >= 1; --t) {
            tag = bptr[t * TAGS + tag];
            path[t - 1] = (unsigned short)tag;
        }
    }
    __builtin_amdgcn_wave_barrier();

    // coalesced path writeback (tags as float32)
    float* pout = out + B + (size_t)b * T;
    for (int t = lane; t < T; t += 64)
        pout[t] = (float)path[t];
}

extern "C" void kernel_launch(void* const* d_in, const int* in_sizes, int n_in,
                              void* d_out, int out_size, void* d_ws, size_t ws_size,
                              hipStream_t stream) {
    const float* feats   = (const float*)d_in[0];
    const float* weights = (const float*)d_in[1];
    const int*   lens    = (const int*)d_in[2];
    float*       out     = (float*)d_out;

    const int B = in_sizes[2];
    const int T = in_sizes[0] / (B * TAGS);

    crf_viterbi<<<dim3(B), dim3(192), 0, stream>>>(feats, weights, lens, out, B, T);
}

// Round 7
// 472.103 us; speedup vs baseline: 1.1494x; 1.1494x over previous
//
#include <hip/hip_runtime.h>

#define TAGS 64
#define MAXT 512
#define NEG  -10000.0f
#define CH   8   // feat prefetch chunk

// Round-13: split the argmax across BLOCKS (not waves), with redundant value
// compute. Post-mortem r2/r5/r6: every 192-thread divergent kernel gets
// 84-96 VGPRs (compiler starves w4[16]+quads ~150 needed) regardless of
// launch bounds -> all producer/consumer tests were void. 64-thread kernels
// reliably get 132 VGPRs (r0/r1/r3). Also: grid 1024 = 4 blocks/CU = 1
// wave/SIMD exactly; more waves require more BLOCKS.
// Design: 2 blocks per batch (grid 2048, 64 thr). Both run the identical
// bit-exact value recurrence (deterministic FP -> same fv stream, zero
// communication). Role r = blockIdx&1 does the argmax only for t==r (mod 2)
// (r3-verified bitwise scan) and streams bptr rows to global ws (coalesced
// 64B wave-stores, off critical path). Per-wave work 293 -> ~214 instr/step
// AND 2 waves/SIMD (tests whether the ~4.4 cyc/instr per-wave cadence is
// arbitration-limited or a hard floor). A second stream-ordered kernel
// (kernel boundary = full visibility, no fences/spins) stages bptr ws->LDS
// and runs the proven serial chase + path writeback.
// Host fallback: ws too small -> round-0 monolith (283 us, verified).

#define F3(a, b, c) fmaxf(fmaxf((a), (b)), (c))
#define M3(a, b, c) min(min((a), (b)), (c))

__global__ __launch_bounds__(64, 1) void crf_forward(
    const float* __restrict__ feats,   // [B, T, K]
    const float* __restrict__ weights, // [K, K] (weights[next][prev])
    const int*   __restrict__ lens,    // [B]
    float*       __restrict__ out,     // [B] scores (paths written by kernel 2)
    unsigned char* __restrict__ gb,    // ws: [B, T, K] backpointers
    int*         __restrict__ bestl,   // ws: [B] argmax of terminal
    int B, int T)
{
    const int b    = blockIdx.x >> 1;
    const int role = blockIdx.x & 1;           // handles t == role (mod 2)
    const int lane = threadIdx.x;              // next tag
    const int len  = lens[b];                  // 1..T

    __shared__ float fv[TAGS];                 // 256 B only -> 8 blocks/CU

    // W row for this lane (as float4 quads)
    float4 w4[16];
    #pragma unroll
    for (int i = 0; i < 16; ++i)
        w4[i] = *reinterpret_cast<const float4*>(weights + lane * TAGS + i * 4);
    const float wEnd = weights[1 * TAGS + lane];  // transition into END

    fv[lane] = (lane == 0) ? 0.0f : NEG;          // START = 0

    const float* fb  = feats + (size_t)b * T * TAGS;
    const int    cap = len * TAGS;                // valid dword count
    unsigned char* gbb = gb + (size_t)b * T * TAGS + lane;

    float nf = NEG;                               // this lane's running fv

    // feat prefetch in registers (r1-verified): chunk c in fcur, c+1 in fnx
    float fcur[CH], fnx[CH];
    #pragma unroll
    for (int i = 0; i < CH; ++i) {
        int o = i * TAGS + lane; if (o >= cap) o = lane;
        fcur[i] = fb[o];
    }
    #pragma unroll
    for (int i = 0; i < CH; ++i) {
        int o = (CH + i) * TAGS + lane; if (o >= cap) o = lane;
        fnx[i] = fb[o];
    }

    auto step = [&](float feat, int t, bool doArg) {
        // gather fv quads (16x ds_read_b128, broadcast, conflict-free)
        float4 fq[16];
        #pragma unroll
        for (int g = 0; g < 16; ++g)
            fq[g] = *reinterpret_cast<const float4*>(&fv[g * 4]);
        float4 c4[16];
        #pragma unroll
        for (int g = 0; g < 16; ++g) {
            c4[g].x = fq[g].x + w4[g].x;
            c4[g].y = fq[g].y + w4[g].y;
            c4[g].z = fq[g].z + w4[g].z;
            c4[g].w = fq[g].w + w4[g].w;
        }
        const float* c = reinterpret_cast<const float*>(c4);

        // value-only max: 3-ary tree (v_max3_f32), depth 4
        float v1[22];
        #pragma unroll
        for (int k = 0; k < 21; ++k) v1[k] = F3(c[3*k], c[3*k+1], c[3*k+2]);
        v1[21] = c[63];
        float v2[8];
        #pragma unroll
        for (int k = 0; k < 7; ++k) v2[k] = F3(v1[3*k], v1[3*k+1], v1[3*k+2]);
        v2[7] = v1[21];
        const float v30 = F3(v2[0], v2[1], v2[2]);
        const float v31 = F3(v2[3], v2[4], v2[5]);
        const float v32 = fmaxf(v2[6], v2[7]);
        const float m   = F3(v30, v31, v32);

        nf = m + feat;                 // emission added after max
        fv[lane] = nf;                 // unblocks step t+1 (same-wave LDS order)

        if (doArg) {                   // wave-uniform branch
            // bitwise first-occurrence argmax (r3-verified):
            // key = (bits(m - c[p]) & ~63) | p ; winner's key == p
            unsigned q[16];
            #pragma unroll
            for (int g = 0; g < 16; ++g) {
                const unsigned k0 = (__float_as_uint(m - c[4*g+0]) & 0xFFFFFFC0u) | (unsigned)(4*g+0);
                const unsigned k1 = (__float_as_uint(m - c[4*g+1]) & 0xFFFFFFC0u) | (unsigned)(4*g+1);
                const unsigned k2 = (__float_as_uint(m - c[4*g+2]) & 0xFFFFFFC0u) | (unsigned)(4*g+2);
                const unsigned k3 = (__float_as_uint(m - c[4*g+3]) & 0xFFFFFFC0u) | (unsigned)(4*g+3);
                q[g] = min(M3(k0, k1, k2), k3);
            }
            const unsigned t0 = M3(q[0],  q[1],  q[2]);
            const unsigned t1 = M3(q[3],  q[4],  q[5]);
            const unsigned t2 = M3(q[6],  q[7],  q[8]);
            const unsigned t3 = M3(q[9],  q[10], q[11]);
            const unsigned t4 = M3(q[12], q[13], q[14]);
            const unsigned idx = min(M3(t0, t1, t2), M3(t3, t4, q[15]));
            gbb[(size_t)t * TAGS] = (unsigned char)idx;  // coalesced 64B row
        }
    };

    const int nfull = len / CH;
    for (int c = 0; c < nfull; ++c) {
        #pragma unroll
        for (int i = 0; i < CH; ++i)
            step(fcur[i], c * CH + i, (i & 1) == role);   // t&1 == i&1 (CH even)
        #pragma unroll
        for (int i = 0; i < CH; ++i) fcur[i] = fnx[i];
        #pragma unroll
        for (int i = 0; i < CH; ++i) {
            int o = (c + 2) * CH * TAGS + i * TAGS + lane;
            if (o >= cap) o = lane;
            fnx[i] = fb[o];
        }
    }
    const int rem = len - nfull * CH;             // 0..7 remainder steps
    #pragma unroll
    for (int i = 0; i < CH; ++i)                  // static indices
        if (i < rem) step(fcur[i], nfull * CH + i, (i & 1) == role);

    if (role != 0) return;

    // terminal = fv + W[END][prev]; first-max argmax via shuffle butterfly
    float tv = nf + wEnd;
    int   ti = lane;
    #pragma unroll
    for (int off = 32; off >= 1; off >>= 1) {
        const float ov = __shfl_xor(tv, off);
        const int   oi = __shfl_xor(ti, off);
        if (ov > tv || (ov == tv && oi < ti)) { tv = ov; ti = oi; }
    }
    if (lane == 0) { out[b] = tv; bestl[b] = ti; }
}

__global__ __launch_bounds__(64, 1) void crf_backtrace(
    const int*           __restrict__ lens,
    const unsigned char* __restrict__ gb,     // ws: [B, T, K] backpointers
    const int*           __restrict__ bestl,  // ws: [B]
    float*               __restrict__ out,    // [B] scores ++ [B*T] paths
    int B, int T)
{
    const int b    = blockIdx.x;
    const int lane = threadIdx.x;
    const int len  = lens[b];

    __shared__ unsigned char  bptr[MAXT * TAGS];  // 32 KB
    __shared__ unsigned short path[MAXT];

    // bulk-stage bptr rows [0, len) ws -> LDS (coalesced uint4)
    const uint4* src = reinterpret_cast<const uint4*>(gb + (size_t)b * T * TAGS);
    uint4*       dst = reinterpret_cast<uint4*>(bptr);
    const int n16 = len * (TAGS / 16);            // uint4 count
    for (int i = lane; i < n16; i += 64) dst[i] = src[i];

    const int bestlast = bestl[b];
    // padding region: path[t] = bestlast for t in [len-1, T)
    for (int t = lane; t < T; t += 64)
        if (t >= len - 1) path[t] = (unsigned short)bestlast;
    __syncthreads();

    // serial chase (lane 0, LDS-resident backpointers) — r0-proven
    if (lane == 0) {
        int tag = bestlast;
        for (int t = len - 1; t >= 1; --t) {
            tag = bptr[t * TAGS + tag];
            path[t - 1] = (unsigned short)tag;
        }
    }
    __syncthreads();

    // coalesced path writeback (tags as float32)
    float* pout = out + B + (size_t)b * T;
    for (int t = lane; t < T; t += 64)
        pout[t] = (float)path[t];
}

// ---------- fallback: round-0 monolith (verified, 283 us/dispatch) ----------
__global__ __launch_bounds__(64, 1) void crf_viterbi(
    const float* __restrict__ feats, const float* __restrict__ weights,
    const int* __restrict__ lens, float* __restrict__ out, int B, int T)
{
    const int b    = blockIdx.x;
    const int lane = threadIdx.x;
    const int len  = lens[b];

    __shared__ float fv[TAGS];
    __shared__ float fbuf[2][CH * TAGS];
    __shared__ unsigned char  bptr[MAXT * TAGS];
    __shared__ unsigned short path[MAXT];

    float4 w4[16];
    #pragma unroll
    for (int i = 0; i < 16; ++i)
        w4[i] = *reinterpret_cast<const float4*>(weights + lane * TAGS + i * 4);
    const float wEnd = weights[1 * TAGS + lane];

    fv[lane] = (lane == 0) ? 0.0f : NEG;
    const float* fb  = feats + (size_t)b * T * TAGS;
    const int    lim = len * TAGS - 4;
    float nf = NEG;

    auto step = [&](int cbuf, int i, int t) {
        const float feat = fbuf[cbuf][i * TAGS + lane];
        float4 fq[16];
        #pragma unroll
        for (int g = 0; g < 16; ++g)
            fq[g] = *reinterpret_cast<const float4*>(&fv[g * 4]);
        float4 c4[16];
        #pragma unroll
        for (int g = 0; g < 16; ++g) {
            c4[g].x = fq[g].x + w4[g].x;
            c4[g].y = fq[g].y + w4[g].y;
            c4[g].z = fq[g].z + w4[g].z;
            c4[g].w = fq[g].w + w4[g].w;
        }
        const float* c = reinterpret_cast<const float*>(c4);
        float v1[22];
        #pragma unroll
        for (int k = 0; k < 21; ++k) v1[k] = F3(c[3*k], c[3*k+1], c[3*k+2]);
        v1[21] = c[63];
        float v2[8];
        #pragma unroll
        for (int k = 0; k < 7; ++k) v2[k] = F3(v1[3*k], v1[3*k+1], v1[3*k+2]);
        v2[7] = v1[21];
        const float m = F3(F3(v2[0], v2[1], v2[2]),
                           F3(v2[3], v2[4], v2[5]), fmaxf(v2[6], v2[7]));
        nf = m + feat;
        fv[lane] = nf;
        unsigned e[64];
        #pragma unroll
        for (int p = 0; p < 64; ++p)
            e[p] = (__float_as_uint(m - c[p]) & 0xFFFFFFC0u) | (unsigned)p;
        unsigned u1[22];
        #pragma unroll
        for (int k = 0; k < 21; ++k) u1[k] = M3(e[3*k], e[3*k+1], e[3*k+2]);
        u1[21] = e[63];
        unsigned u2[8];
        #pragma unroll
        for (int k = 0; k < 7; ++k) u2[k] = M3(u1[3*k], u1[3*k+1], u1[3*k+2]);
        u2[7] = u1[21];
        const unsigned idx = M3(M3(u2[0], u2[1], u2[2]),
                                M3(u2[3], u2[4], u2[5]), min(u2[6], u2[7]));
        bptr[t * TAGS + lane] = (unsigned char)idx;
    };

    {
        int o0 = 4 * lane;        if (o0 > lim) o0 = lim;
        int o1 = 256 + 4 * lane;  if (o1 > lim) o1 = lim;
        *reinterpret_cast<float4*>(&fbuf[0][4 * lane])       = *reinterpret_cast<const float4*>(fb + o0);
        *reinterpret_cast<float4*>(&fbuf[0][256 + 4 * lane]) = *reinterpret_cast<const float4*>(fb + o1);
    }
    float4 n0, n1;
    {
        int o0 = CH * TAGS + 4 * lane;        if (o0 > lim) o0 = lim;
        int o1 = CH * TAGS + 256 + 4 * lane;  if (o1 > lim) o1 = lim;
        n0 = *reinterpret_cast<const float4*>(fb + o0);
        n1 = *reinterpret_cast<const float4*>(fb + o1);
    }
    int cb = 0;
    const int nfull = len / CH;
    for (int c = 0; c < nfull; ++c) {
        #pragma unroll
        for (int i = 0; i < CH; ++i) step(cb, i, c * CH + i);
        *reinterpret_cast<float4*>(&fbuf[cb ^ 1][4 * lane])       = n0;
        *reinterpret_cast<float4*>(&fbuf[cb ^ 1][256 + 4 * lane]) = n1;
        {
            int o0 = (c + 2) * CH * TAGS + 4 * lane;        if (o0 > lim) o0 = lim;
            int o1 = (c + 2) * CH * TAGS + 256 + 4 * lane;  if (o1 > lim) o1 = lim;
            n0 = *reinterpret_cast<const float4*>(fb + o0);
            n1 = *reinterpret_cast<const float4*>(fb + o1);
        }
        cb ^= 1;
    }
    const int rem = len - nfull * CH;
    for (int i = 0; i < rem; ++i) step(cb, i, nfull * CH + i);

    float tv = nf + wEnd;
    int   ti = lane;
    #pragma unroll
    for (int off = 32; off >= 1; off >>= 1) {
        const float ov = __shfl_xor(tv, off);
        const int   oi = __shfl_xor(ti, off);
        if (ov > tv || (ov == tv && oi < ti)) { tv = ov; ti = oi; }
    }
    if (lane == 0) out[b] = tv;
    const int bestlast = ti;
    for (int t = lane; t < T; t += 64)
        if (t >= len - 1) path[t] = (unsigned short)bestlast;
    __builtin_amdgcn_wave_barrier();
    if (lane == 0) {
        int tag = bestlast;
        for (int t = len - 1; t >= 1; --t) {
            tag = bptr[t * TAGS + tag];
            path[t - 1] = (unsigned short)tag;
        }
    }
    __builtin_amdgcn_wave_barrier();
    float* pout = out + B + (size_t)b * T;
    for (int t = lane; t < T; t += 64)
        pout[t] = (float)path[t];
}

extern "C" void kernel_launch(void* const* d_in, const int* in_sizes, int n_in,
                              void* d_out, int out_size, void* d_ws, size_t ws_size,
                              hipStream_t stream) {
    const float* feats   = (const float*)d_in[0];
    const float* weights = (const float*)d_in[1];
    const int*   lens    = (const int*)d_in[2];
    float*       out     = (float*)d_out;

    const int B = in_sizes[2];
    const int T = in_sizes[0] / (B * TAGS);

    const size_t need = (size_t)B * T * TAGS + (size_t)B * sizeof(int);
    if (d_ws != nullptr && ws_size >= need) {
        unsigned char* gb    = (unsigned char*)d_ws;
        int*           bestl = (int*)((unsigned char*)d_ws + (size_t)B * T * TAGS);
        crf_forward<<<dim3(2 * B), dim3(64), 0, stream>>>(feats, weights, lens, out, gb, bestl, B, T);
        crf_backtrace<<<dim3(B), dim3(64), 0, stream>>>(lens, gb, bestl, out, B, T);
    } else {
        crf_viterbi<<<dim3(B), dim3(64), 0, stream>>>(feats, weights, lens, out, B, T);
    }
}